// Round 16
// baseline (94.607 us; speedup 1.0000x reference)
//
#include <hip/hip_runtime.h>

#define NPIX  65536
#define NG    512
#define NB    4
#define MAXD  362.03867196751236f
#define WRAD  16                  // Chebyshev window radius for term-2 fast path
#define WDIM  33                  // 2*WRAD+1
#define WCNT  1089                // WDIM*WDIM
#define SAFE_Q (15.0f - MAXD)     // window min <= this => provably global
#define NBLK_T1 128               // term-1: 8 rows per block
#define NBLK_T2 (NB*NG)           // 2048

// ws layout (floats):
//   [0,   128) : term-1 per-block partial sum of p*min_d   (img = blk>>5)
//   [512, 640) : term-1 per-block partial sum of p
//   [1024,3072): per-(b,g) min of p*(d - MAXD)

#define REPS 4                    // diagnostic amplification factor

__device__ __forceinline__ float wave_sum(float v){
  #pragma unroll
  for (int o = 32; o > 0; o >>= 1) v += __shfl_down(v, o, 64);
  return v;
}
__device__ __forceinline__ float wave_min(float v){
  #pragma unroll
  for (int o = 32; o > 0; o >>= 1) v = fminf(v, __shfl_down(v, o, 64));
  return v;
}

// ---------- term-1, amplified x4 (diagnostic) ----------
__global__ __launch_bounds__(256) void k_t1(const float* __restrict__ prob,
                                            const int* __restrict__ gt,
                                            float* __restrict__ wsout){
  const int tid = threadIdx.x;
  __shared__ float2 gsab[NG];
  __shared__ float red[8];
  const int b  = blockIdx.x >> 5;                 // 32 blocks per image
  const int hp = (blockIdx.x & 31) << 3;          // rows hp .. hp+7
  const float wf = (float)tid;

  const int2* gtp = ((const int2*)gt) + b*NG;
  #pragma unroll
  for (int s = 0; s < 2; ++s){
    const int g = tid + 256*s;
    const int2 q = gtp[g];
    gsab[g] = make_float2(-2.0f*(float)q.x, -2.0f*(float)q.y);
  }
  __syncthreads();

  float hf[8];
  #pragma unroll
  for (int r = 0; r < 8; ++r) hf[r] = (float)(hp + r);

  for (int rep = 0; rep < REPS; ++rep){
    float m[8];
    #pragma unroll
    for (int r = 0; r < 8; ++r){
      m[r] = 3e38f;
      asm volatile("" : "+v"(m[r]));              // opaque init: forces re-execution per rep
    }

    #pragma unroll 4
    for (int k = 0; k < 256; ++k){
      const float2 q0 = gsab[2*k + 0];            // wave-uniform b64 broadcast
      const float2 q1 = gsab[2*k + 1];
      const float sc0 = fmaf(q0.y, q0.y, q0.x*q0.x) * 0.25f;  // gh^2+gw^2, exact
      const float sc1 = fmaf(q1.y, q1.y, q1.x*q1.x) * 0.25f;
      const float u0  = fmaf(q0.y, wf, sc0);      // sc - 2gw*w, exact int
      const float u1  = fmaf(q1.y, wf, sc1);
      #pragma unroll
      for (int r = 0; r < 8; ++r){
        const float t0 = fmaf(q0.x, hf[r], u0);   // d2 - (h^2+w^2), exact int
        const float t1 = fmaf(q1.x, hf[r], u1);
        m[r] = fminf(fminf(m[r], t0), t1);        // v_min3
      }
    }

    if (rep == REPS - 1){
      float spd = 0.0f, sp = 0.0f;
      const float w2 = (float)(tid*tid);
      #pragma unroll
      for (int r = 0; r < 8; ++r){
        const float d = __builtin_amdgcn_sqrtf(m[r] + fmaf(hf[r], hf[r], w2));
        const float p = prob[b*NPIX + (hp + r)*256 + tid];
        spd = fmaf(p, d, spd);
        sp += p;
      }
      spd = wave_sum(spd);
      sp  = wave_sum(sp);
      const int wid = tid >> 6, lane = tid & 63;
      if (lane == 0){ red[wid] = spd; red[4+wid] = sp; }
      __syncthreads();
      if (tid == 0){
        wsout[blockIdx.x]       = (red[0]+red[1]) + (red[2]+red[3]);
        wsout[512 + blockIdx.x] = (red[4]+red[5]) + (red[6]+red[7]);
      }
    } else {
      #pragma unroll
      for (int r = 0; r < 8; ++r) asm volatile("" :: "v"(m[r]));  // keep live (no DCE)
    }
  }
}

// ---------- term-2, amplified x4 (diagnostic) ----------
__global__ __launch_bounds__(256) void k_t2(const float* __restrict__ prob,
                                            const int* __restrict__ gt,
                                            float* __restrict__ wsout){
  const int tid = threadIdx.x;
  __shared__ float red[8];
  const int idx = blockIdx.x;                     // b*NG + g
  const int b   = idx >> 9;
  const int gh  = gt[idx*2 + 0];
  const int gw  = gt[idx*2 + 1];

  float qm = 3e38f;
  for (int rep = 0; rep < REPS; ++rep){
    float q = 3e38f;
    asm volatile("" : "+v"(q));                   // opaque init
    int pbase = b*NPIX;
    asm volatile("" : "+v"(pbase));               // opaque base: loads reissued per rep
    for (int i = tid; i < WCNT; i += 256){
      const int r  = i / WDIM;
      const int c  = i - r*WDIM;
      const int hh = gh - WRAD + r;
      const int ww = gw - WRAD + c;
      if ((unsigned)hh < 256u && (unsigned)ww < 256u){
        const float p  = prob[pbase + hh*256 + ww];
        const int  dh  = r - WRAD, dw = c - WRAD;
        const float d  = __builtin_amdgcn_sqrtf((float)(dh*dh + dw*dw));
        q = fminf(q, fmaf(p, d, p * (-MAXD)));
      }
    }
    if (rep == REPS - 1) qm = q;
    else asm volatile("" :: "v"(q));              // keep live (no DCE)
  }

  qm = wave_min(qm);
  const int wid = tid >> 6, lane = tid & 63;
  if (lane == 0) red[wid] = qm;
  __syncthreads();
  float qf = fminf(fminf(red[0], red[1]), fminf(red[2], red[3]));

  if (qf > SAFE_Q){
    // exact fallback: full-image rescan (rare; keeps kernel exact)
    const float ghf = (float)gh, gwf = (float)gw;
    const float aa  = -2.0f*ghf;
    const float wf  = (float)tid;
    const float bc  = fmaf(-2.0f*gwf, wf, fmaf(ghf, ghf, gwf*gwf));
    const float wsq = wf*wf;
    float q2 = 3e38f;
    const float* pr = prob + b*NPIX + tid;
    #pragma unroll 4
    for (int i = 0; i < 256; ++i){
      const float p   = pr[i*256];
      const float hfi = (float)i;
      const float d2v = fmaf(aa, hfi, fmaf(hfi, hfi, wsq) + bc);
      const float d   = __builtin_amdgcn_sqrtf(d2v);
      q2 = fminf(q2, fmaf(p, d, p * (-MAXD)));
    }
    q2 = wave_min(q2);
    __syncthreads();
    if (lane == 0) red[wid] = q2;
    __syncthreads();
    qf = fminf(fminf(red[0], red[1]), fminf(red[2], red[3]));
  }
  if (tid == 0) wsout[1024 + idx] = qf;
}

// ---------- finish: fully parallel deterministic reduction ----------
__global__ __launch_bounds__(256) void k_finish(const float* __restrict__ ws,
                                                float* __restrict__ out){
  const int tid  = threadIdx.x;
  const int w    = tid >> 6;
  const int lane = tid & 63;
  __shared__ float redT2[4];
  __shared__ float t1sh[NB];

  float s = 0.0f;
  #pragma unroll
  for (int j = 0; j < 8; ++j) s += ws[1024 + tid*8 + j];
  s = wave_sum(s);
  if (lane == 0) redT2[w] = s;

  float v = (lane < 32) ? ws[w*32 + lane] : ws[512 + w*32 + (lane - 32)];
  #pragma unroll
  for (int o = 16; o > 0; o >>= 1) v += __shfl_down(v, o, 32);
  const float ppv = __shfl(v, 32, 64);
  if (lane == 0) t1sh[w] = v / (ppv + 1e-6f);
  __syncthreads();

  if (tid == 0){
    const float s2    = (redT2[0]+redT2[1]) + (redT2[2]+redT2[3]);
    const float term2 = MAXD + s2 * (1.0f/2048.0f);
    const float term1 = ((t1sh[0]+t1sh[1]) + (t1sh[2]+t1sh[3])) * 0.25f;
    out[0] = term1 + term2;
  }
}

extern "C" void kernel_launch(void* const* d_in, const int* in_sizes, int n_in,
                              void* d_out, int out_size, void* d_ws, size_t ws_size,
                              hipStream_t stream) {
  const float* prob = (const float*)d_in[0];
  const int*   gt   = (const int*)d_in[1];
  float* out = (float*)d_out;
  float* ws  = (float*)d_ws;

  hipLaunchKernelGGL(k_t1,     dim3(NBLK_T1), dim3(256), 0, stream, prob, gt, ws);
  hipLaunchKernelGGL(k_t2,     dim3(NBLK_T2), dim3(256), 0, stream, prob, gt, ws);
  hipLaunchKernelGGL(k_finish, dim3(1),       dim3(256), 0, stream, ws, out);
}

// Round 17
// 17.283 us; speedup vs baseline: 5.4739x; 5.4739x over previous
//
#include <hip/hip_runtime.h>

#define NPIX  65536
#define NG    512
#define NB    4
#define MAXD  362.03867196751236f
#define WRAD  16                  // term-2 Chebyshev window radius
#define WDIM  33                  // 2*WRAD+1
#define WCNT  1089                // WDIM*WDIM
#define SAFE_Q (15.0f - MAXD)     // window min <= this => provably global
#define NBLK_T1 128               // term-1: 8 rows per block
#define NBLK_T2 (NB*NG)           // 2048
#define NBLK_MAIN (NBLK_T1 + NBLK_T2)
#define BRAD 32                   // term-1 row-band radius: out-of-band => d > 32
#define BSPAN 72                  // band rows: [hp-32, hp+39]
#define BCAP 352                  // band list capacity (mean 144, sd 10 -> P(overflow)~0)

// ws layout (floats):
//   [0,   128) : term-1 per-block partial sum of p*min_d   (img = blk>>5)
//   [512, 640) : term-1 per-block partial sum of p
//   [1024,3072): per-(b,g) min of p*(d - MAXD)

__device__ __forceinline__ float wave_sum(float v){
  #pragma unroll
  for (int o = 32; o > 0; o >>= 1) v += __shfl_down(v, o, 64);
  return v;
}
__device__ __forceinline__ float wave_min(float v){
  #pragma unroll
  for (int o = 32; o > 0; o >>= 1) v = fminf(v, __shfl_down(v, o, 64));
  return v;
}

// ---------- main: term-1 (blocks 0..127) + term-2 windows (blocks 128..2175) ----------
__global__ __launch_bounds__(256) void k_main(const float* __restrict__ prob,
                                              const int* __restrict__ gt,
                                              float* __restrict__ wsout){
  const int tid = threadIdx.x;

  if (blockIdx.x < NBLK_T1){
    // ----- term 1: block = (b, 8-row group); thread = column -----
    // Row-band pruning: only gt with gh in [hp-32, hp+39] tested (exp ~144/512).
    // Certified iff band-min d2 <= 1024 (out-of-band => d2 > 1024, exact ints).
    // Any uncertified pixel (or list overflow) => full 512-point rescan (exact).
    __shared__ float2 gsab[NG];        // all 512 (fallback path)
    __shared__ float2 bsab[BCAP + 1];  // band list + sentinel slot
    __shared__ float red[8];
    __shared__ int bcnt, ovf, anybad;
    const int b  = blockIdx.x >> 5;                 // 32 blocks per image
    const int hp = (blockIdx.x & 31) << 3;          // rows hp .. hp+7
    const float wf = (float)tid;

    if (tid == 0){ bcnt = 0; ovf = 0; anybad = 0; }
    __syncthreads();

    const int2* gtp = ((const int2*)gt) + b*NG;
    #pragma unroll
    for (int s = 0; s < 2; ++s){
      const int g = tid + 256*s;
      const int2 q = gtp[g];
      const float2 v2 = make_float2(-2.0f*(float)q.x, -2.0f*(float)q.y);
      gsab[g] = v2;
      if ((unsigned)(q.x - (hp - BRAD)) < (unsigned)BSPAN){
        const int pos = atomicAdd(&bcnt, 1);
        if (pos < BCAP) bsab[pos] = v2; else ovf = 1;
      }
    }
    __syncthreads();
    const int Lc = min(bcnt, BCAP);
    if (tid == 0) bsab[Lc] = make_float2(-20000.0f, -20000.0f);  // sentinel (d2 ~ 2e8)
    __syncthreads();
    const int pairs = (Lc + 1) >> 1;

    float hf[8], m[8];
    #pragma unroll
    for (int r = 0; r < 8; ++r){ hf[r] = (float)(hp + r); m[r] = 3e38f; }

    #pragma unroll 2
    for (int k = 0; k < pairs; ++k){
      const float2 q0 = bsab[2*k + 0];              // wave-uniform broadcast
      const float2 q1 = bsab[2*k + 1];
      const float sc0 = fmaf(q0.y, q0.y, q0.x*q0.x) * 0.25f;  // gh^2+gw^2, exact
      const float sc1 = fmaf(q1.y, q1.y, q1.x*q1.x) * 0.25f;
      const float u0  = fmaf(q0.y, wf, sc0);        // sc - 2gw*w, exact int
      const float u1  = fmaf(q1.y, wf, sc1);
      #pragma unroll
      for (int r = 0; r < 8; ++r){
        const float t0 = fmaf(q0.x, hf[r], u0);     // d2 - (h^2+w^2), exact int
        const float t1 = fmaf(q1.x, hf[r], u1);
        m[r] = fminf(fminf(m[r], t0), t1);          // v_min3
      }
    }

    // certification: v[r] = true d2; uncertified if > 1024 (= BRAD^2)
    const float w2 = (float)(tid*tid);
    float v[8];
    int bad = ovf;
    #pragma unroll
    for (int r = 0; r < 8; ++r){
      v[r] = m[r] + fmaf(hf[r], hf[r], w2);
      bad |= (v[r] > 1024.0f);
    }
    if (bad) anybad = 1;                             // benign race
    __syncthreads();

    if (anybad){
      // exact fallback: full 512-point scan (block-uniform; ~never on real data)
      #pragma unroll
      for (int r = 0; r < 8; ++r) m[r] = 3e38f;
      #pragma unroll 4
      for (int k = 0; k < 256; ++k){
        const float2 q0 = gsab[2*k + 0];
        const float2 q1 = gsab[2*k + 1];
        const float sc0 = fmaf(q0.y, q0.y, q0.x*q0.x) * 0.25f;
        const float sc1 = fmaf(q1.y, q1.y, q1.x*q1.x) * 0.25f;
        const float u0  = fmaf(q0.y, wf, sc0);
        const float u1  = fmaf(q1.y, wf, sc1);
        #pragma unroll
        for (int r = 0; r < 8; ++r){
          const float t0 = fmaf(q0.x, hf[r], u0);
          const float t1 = fmaf(q1.x, hf[r], u1);
          m[r] = fminf(fminf(m[r], t0), t1);
        }
      }
      #pragma unroll
      for (int r = 0; r < 8; ++r) v[r] = m[r] + fmaf(hf[r], hf[r], w2);
    }

    float spd = 0.0f, sp = 0.0f;
    #pragma unroll
    for (int r = 0; r < 8; ++r){
      const float d = __builtin_amdgcn_sqrtf(v[r]);
      const float p = prob[b*NPIX + (hp + r)*256 + tid];   // coalesced
      spd = fmaf(p, d, spd);
      sp += p;
    }

    spd = wave_sum(spd);
    sp  = wave_sum(sp);
    const int wid = tid >> 6, lane = tid & 63;
    if (lane == 0){ red[wid] = spd; red[4+wid] = sp; }
    __syncthreads();
    if (tid == 0){
      wsout[blockIdx.x]       = (red[0]+red[1]) + (red[2]+red[3]);
      wsout[512 + blockIdx.x] = (red[4]+red[5]) + (red[6]+red[7]);
    }
  } else {
    // ----- term 2: one (b,g) per block; window + exact in-block fallback -----
    __shared__ float red[8];
    const int idx = blockIdx.x - NBLK_T1;           // b*NG + g
    const int b   = idx >> 9;
    const int gh  = gt[idx*2 + 0];
    const int gw  = gt[idx*2 + 1];

    float qm = 3e38f;
    for (int i = tid; i < WCNT; i += 256){
      const int r  = i / WDIM;
      const int c  = i - r*WDIM;
      const int hh = gh - WRAD + r;
      const int ww = gw - WRAD + c;
      if ((unsigned)hh < 256u && (unsigned)ww < 256u){
        const float p  = prob[b*NPIX + hh*256 + ww];
        const int  dh  = r - WRAD, dw = c - WRAD;
        const float d  = __builtin_amdgcn_sqrtf((float)(dh*dh + dw*dw));
        qm = fminf(qm, fmaf(p, d, p * (-MAXD)));
      }
    }
    qm = wave_min(qm);
    const int wid = tid >> 6, lane = tid & 63;
    if (lane == 0) red[wid] = qm;
    __syncthreads();
    float qf = fminf(fminf(red[0], red[1]), fminf(red[2], red[3]));

    if (qf > SAFE_Q){
      // exact fallback: full-image rescan (rare; keeps kernel exact)
      const float ghf = (float)gh, gwf = (float)gw;
      const float aa  = -2.0f*ghf;
      const float wf  = (float)tid;
      const float bc  = fmaf(-2.0f*gwf, wf, fmaf(ghf, ghf, gwf*gwf));
      const float wsq = wf*wf;
      float q2 = 3e38f;
      const float* pr = prob + b*NPIX + tid;
      #pragma unroll 4
      for (int i = 0; i < 256; ++i){
        const float p   = pr[i*256];
        const float hfi = (float)i;
        const float d2v = fmaf(aa, hfi, fmaf(hfi, hfi, wsq) + bc);
        const float d   = __builtin_amdgcn_sqrtf(d2v);
        q2 = fminf(q2, fmaf(p, d, p * (-MAXD)));
      }
      q2 = wave_min(q2);
      __syncthreads();
      if (lane == 0) red[wid] = q2;
      __syncthreads();
      qf = fminf(fminf(red[0], red[1]), fminf(red[2], red[3]));
    }
    if (tid == 0) wsout[1024 + idx] = qf;
  }
}

// ---------- finish: fully parallel deterministic reduction ----------
__global__ __launch_bounds__(256) void k_finish(const float* __restrict__ ws,
                                                float* __restrict__ out){
  const int tid  = threadIdx.x;
  const int w    = tid >> 6;      // wave id == image id for term-1 part
  const int lane = tid & 63;
  __shared__ float redT2[4];
  __shared__ float t1sh[NB];

  // term-2 sum: 2048 values, 8 per thread, coalesced
  float s = 0.0f;
  #pragma unroll
  for (int j = 0; j < 8; ++j) s += ws[1024 + tid*8 + j];
  s = wave_sum(s);
  if (lane == 0) redT2[w] = s;

  // term-1: wave w = image w; lanes 0-31 carry pd partials, 32-63 carry pp
  float v = (lane < 32) ? ws[w*32 + lane] : ws[512 + w*32 + (lane - 32)];
  #pragma unroll
  for (int o = 16; o > 0; o >>= 1) v += __shfl_down(v, o, 32);
  const float ppv = __shfl(v, 32, 64);              // pp total (from lane 32)
  if (lane == 0) t1sh[w] = v / (ppv + 1e-6f);
  __syncthreads();

  if (tid == 0){
    const float s2    = (redT2[0]+redT2[1]) + (redT2[2]+redT2[3]);
    const float term2 = MAXD + s2 * (1.0f/2048.0f);
    const float term1 = ((t1sh[0]+t1sh[1]) + (t1sh[2]+t1sh[3])) * 0.25f;
    out[0] = term1 + term2;
  }
}

extern "C" void kernel_launch(void* const* d_in, const int* in_sizes, int n_in,
                              void* d_out, int out_size, void* d_ws, size_t ws_size,
                              hipStream_t stream) {
  const float* prob = (const float*)d_in[0];
  const int*   gt   = (const int*)d_in[1];
  float* out = (float*)d_out;
  float* ws  = (float*)d_ws;

  hipLaunchKernelGGL(k_main,   dim3(NBLK_MAIN), dim3(256), 0, stream, prob, gt, ws);
  hipLaunchKernelGGL(k_finish, dim3(1),         dim3(256), 0, stream, ws, out);
}